// Round 1
// baseline (140.080 us; speedup 1.0000x reference)
//
#include <hip/hip_runtime.h>

#define NTHREADS 1024
#define NC 64

__device__ __forceinline__ float sigmoidf_(float x) {
    return 1.0f / (1.0f + expf(-x));
}

// One block per (batch_row, half). Each block simulates the FULL row of D
// neurons (cascade couples the whole row) but writes only its half of the
// outputs. Duplicated compute is cheap; this doubles active CUs (256 blocks
// on 256 CUs) vs a 128-block layout.
//
// Neuron->thread map: n in [0,8), d = 4*tid + (n>>2)*(D/2) + (n&3).
// So each thread owns two float4-contiguous groups -> vectorized x loads and
// output stores.
__global__ __launch_bounds__(NTHREADS, 1)
void lif_persistent(const float* __restrict__ x,       // [T,B,D]
                    const float* __restrict__ th_raw,  // [D]
                    const float* __restrict__ bm_raw,  // [1]
                    const float* __restrict__ bs_raw,  // [1]
                    const float* __restrict__ nw,      // [NC,NC]
                    const float* __restrict__ gain,    // [NC]
                    const int*   __restrict__ cids,    // [D]
                    float* __restrict__ out_s,         // [T,B,D]
                    float* __restrict__ out_v,         // [T,B,D]
                    int T, int B, int D, float inv_pc)
{
    __shared__ float sW[NC * NC];   // sigmoid(neighbor_weights), row-major [c][c2]
    __shared__ float sGain[NC];
    __shared__ float sCf[NC];       // raw spike counts per cluster
    __shared__ float sNs[NC];       // neighbor signal per cluster

    const int tid  = threadIdx.x;
    const int bid  = blockIdx.x;
    const int b    = bid % B;        // siblings are bid and bid+B -> same XCD (mod 8)
    const int half = bid / B;        // 0: d in [0,D/2), 1: d in [D/2,D)
    const int Dh   = D >> 1;

    for (int i = tid; i < NC * NC; i += NTHREADS) sW[i] = sigmoidf_(nw[i]);
    if (tid < NC) sGain[tid] = gain[tid];

    const float bm  = fminf(fmaxf(sigmoidf_(bm_raw[0]), 0.8f), 0.98f);
    const float omb = __fsub_rn(1.0f, bm);
    const float bs  = sigmoidf_(bs_raw[0]);

    float v[8], isyn[8], th[8], sv[8];
    int refr[8], cid[8];
#pragma unroll
    for (int n = 0; n < 8; ++n) {
        const int d = 4 * tid + (n >> 2) * Dh + (n & 3);
        v[n] = 0.0f; isyn[n] = 0.0f; refr[n] = 0;
        th[n]  = fminf(fmaxf(th_raw[d], 0.05f), 0.5f);
        cid[n] = cids[d];
    }
    __syncthreads();   // sW/sGain ready

    for (int t = 0; t < T; ++t) {
        const size_t base = ((size_t)t * B + b) * D;
        const float4 xv0 = *(const float4*)(x + base + 4 * tid);
        const float4 xv1 = *(const float4*)(x + base + Dh + 4 * tid);
        const float xv[8] = {xv0.x, xv0.y, xv0.z, xv0.w,
                             xv1.x, xv1.y, xv1.z, xv1.w};

        // previous step's matvec (last reader of sCf) finished before the
        // previous step's post-matvec barrier, so zeroing here is race-free
        if (tid < NC) sCf[tid] = 0.0f;
        __syncthreads();   // (a) sCf zeroed

#pragma unroll
        for (int n = 0; n < 8; ++n) {
            // exact numpy fp32 op order: no fma contraction
            isyn[n] = __fadd_rn(__fmul_rn(bs, isyn[n]), xv[n]);
            const float nv = __fadd_rn(__fmul_rn(bm, v[n]),
                                       __fmul_rn(omb, isyn[n]));
            const float vm = (refr[n] > 0) ? -0.1f : nv;
            const float s  = (vm >= th[n]) ? 1.0f : 0.0f;
            v[n]  = vm;
            sv[n] = s;
            if (s != 0.0f) atomicAdd(&sCf[cid[n]], 1.0f);
        }
        __syncthreads();   // (b) all spike counts in

        if (tid < NC) {
            float acc = 0.0f;
#pragma unroll 8
            for (int c2 = 0; c2 < NC; ++c2)
                acc = __fadd_rn(acc,
                      __fmul_rn(__fmul_rn(sCf[c2], inv_pc), sW[tid * NC + c2]));
            sNs[tid] = __fmul_rn(acc, sGain[tid]);
        }
        __syncthreads();   // (c) sNs ready

#pragma unroll
        for (int n = 0; n < 8; ++n) {
            isyn[n] = __fadd_rn(isyn[n], sNs[cid[n]]);
            v[n]    = __fsub_rn(v[n], __fmul_rn(sv[n], th[n]));
            refr[n] = (sv[n] > 0.0f) ? 2 : max(refr[n] - 1, 0);
        }

        // write only our half, vectorized
        const int o = half * 4;
        const float4 so = make_float4(sv[o], sv[o + 1], sv[o + 2], sv[o + 3]);
        const float4 vo = make_float4(v[o],  v[o + 1],  v[o + 2],  v[o + 3]);
        *(float4*)(out_s + base + half * Dh + 4 * tid) = so;
        *(float4*)(out_v + base + half * Dh + 4 * tid) = vo;
    }
}

extern "C" void kernel_launch(void* const* d_in, const int* in_sizes, int n_in,
                              void* d_out, int out_size, void* d_ws, size_t ws_size,
                              hipStream_t stream) {
    const float* x    = (const float*)d_in[0];
    const float* th   = (const float*)d_in[1];
    const float* bm   = (const float*)d_in[2];
    const float* bs   = (const float*)d_in[3];
    const float* nw   = (const float*)d_in[4];
    const float* gain = (const float*)d_in[5];
    const int*   cids = (const int*)d_in[6];

    const int D  = in_sizes[1];          // 8192
    const int TB = in_sizes[0] / D;      // 1024
    const int T  = 8;
    const int B  = TB / T;               // 128

    float* out_s = (float*)d_out;
    float* out_v = out_s + (size_t)T * B * D;

    int per_cluster = D / NC; if (per_cluster < 1) per_cluster = 1;
    const float inv_pc = 1.0f / (float)per_cluster;

    dim3 grid(2 * B), block(NTHREADS);
    hipLaunchKernelGGL(lif_persistent, grid, block, 0, stream,
                       x, th, bm, bs, nw, gain, cids,
                       out_s, out_v, T, B, D, inv_pc);
}